// Round 3
// baseline (251.202 us; speedup 1.0000x reference)
//
#include <hip/hip_runtime.h>
#include <math.h>

#define DT   0.1f
#define HDT  0.005f
#define T_HIST 20
#define LEN_PRED 30

typedef __attribute__((ext_vector_type(8))) short bfrag8;   // 8 bf16 = 4 VGPRs
typedef __attribute__((ext_vector_type(4))) float f32x4;
typedef __attribute__((ext_vector_type(4))) unsigned int u32x4;

// d_ws layout (bytes)
#define WS_FRAG   0u        // 96 frags * 512 bf16 * 2B = 98304 (48 frags = 49152 per phase)
#define WS_WIN    98304u    // 2 frags * 1024B
#define WS_WOUT   100352u   // 1 frag * 1024B
#define WS_BIAS   101376u   // 2*3*32*4 floats = 3072B  ([ph][l][col][gate], b128-readable)

// LDS: one phase of frags (49152) + one phase of bias (1536)
#define LDS_BIAS  49152
#define LDS_SIZE  50688

static __device__ __forceinline__ unsigned short f2bf(float x) {
    union { float f; unsigned int u; } v; v.f = x;
    unsigned int r = v.u + 0x7fffu + ((v.u >> 16) & 1u);   // RNE
    return (unsigned short)(r >> 16);
}

static __device__ __forceinline__ unsigned int cvtpk(float lo, float hi) {
    unsigned int r;
    asm("v_cvt_pk_bf16_f32 %0, %1, %2" : "=v"(r) : "v"(lo), "v"(hi));
    return r;
}

// ---------------- weight prep ----------------
// Layer frag (ph,l,c,t): A[p][k] = W[gate*32+feat][k], gate=p&3, feat=8*(p>>2)+t.
// With D-layout row=q*4+r: lane (q,m) tile t reg r -> gate r of cell feat 8q+t,
// so the packed c/h vectors are ALREADY the next MFMA's B-fragment (zero movement).
// Win frag (t): feat = 8*(p>>2)+4t+(p&3) -> lane (q,m) holds x0 feats 8q..8q+7.
// Bias: [ph][l][col=feat][r=gate] so kernel reads one f32x4 per (l,tile).
__global__ void prep_kernel(const float* __restrict__ Win_W,
                            const float* __restrict__ eWih, const float* __restrict__ eWhh,
                            const float* __restrict__ ebih, const float* __restrict__ ebhh,
                            const float* __restrict__ dWih, const float* __restrict__ dWhh,
                            const float* __restrict__ dbih, const float* __restrict__ dbhh,
                            const float* __restrict__ Wout_W,
                            char* __restrict__ ws)
{
    int i = blockIdx.x * blockDim.x + threadIdx.x;
    if (i < 49152) {
        int fi = i >> 9, within = i & 511;
        int lane = within >> 3, jj = within & 7;
        int t = fi & 7, c = (fi >> 3) & 1;
        int pl = fi >> 4;                 // ph*3 + l
        int l = pl % 3, ph = pl / 3;
        int p = lane & 15, q2 = lane >> 4;
        int gate = p & 3;
        int feat = 8 * (p >> 2) + t;
        int row = gate * 32 + feat;
        int k = q2 * 8 + jj;
        const float* W = (c == 0) ? (ph ? dWih : eWih) : (ph ? dWhh : eWhh);
        ((unsigned short*)(ws + WS_FRAG))[i] = f2bf(W[l * 4096 + row * 32 + k]);
    } else if (i < 50176) {
        int i2 = i - 49152;
        int t = i2 >> 9, within = i2 & 511;
        int lane = within >> 3, jj = within & 7;
        int p = lane & 15, q2 = lane >> 4;
        int feat = 8 * (p >> 2) + 4 * t + (p & 3);
        int k = q2 * 8 + jj;
        float v = (k < 24) ? Win_W[feat * 24 + k] : 0.f;
        ((unsigned short*)(ws + WS_WIN))[i2] = f2bf(v);
    } else if (i < 50688) {
        int i3 = i - 50176;
        int lane = i3 >> 3, jj = i3 & 7;
        int p = lane & 15, q2 = lane >> 4;
        float v = (p < 4) ? Wout_W[p * 32 + q2 * 8 + jj] : 0.f;
        ((unsigned short*)(ws + WS_WOUT))[i3] = f2bf(v);
    } else if (i < 51456) {
        int b = i - 50688;                 // 768 entries: [ph][l][col][r]
        int ph = b / 384, rem = b % 384;
        int l = rem >> 7, w2 = rem & 127;
        int col = w2 >> 2, r = w2 & 3;
        const float* bi = ph ? dbih : ebih;
        const float* bh = ph ? dbhh : ebhh;
        ((float*)(ws + WS_BIAS))[b] = bi[l * 128 + r * 32 + col] + bh[l * 128 + r * 32 + col];
    }
}

// ---------------- main kernel: ONE WAVE per 16 batch elems ----------------
// Recurrence register-resident; weights/biases BLOCK-RESIDENT IN LDS (shared,
// re-read per use via ds_read_b128) so the register file holds only state.
// No barriers in the steady state, no cross-wave traffic except 4 __shfl per
// decoder step.
__launch_bounds__(64, 1)
__global__ void kalman_lstm_kernel(const float* __restrict__ hist,
                                   const float* __restrict__ max_ax, const float* __restrict__ max_ay,
                                   const float* __restrict__ vstd, const float* __restrict__ astd,
                                   const float* __restrict__ Rx_, const float* __restrict__ Ry_,
                                   const float* __restrict__ Gx, const float* __restrict__ Gy,
                                   const float* __restrict__ Win_b, const float* __restrict__ Wout_b,
                                   const char* __restrict__ ws, float* __restrict__ out)
{
    __shared__ __align__(16) char lds[LDS_SIZE];

    const int lane = threadIdx.x;
    const int q    = lane >> 4;
    const int m    = lane & 15;
    const int be   = blockIdx.x * 16 + m;
    const f32x4 zero4 = {0.f, 0.f, 0.f, 0.f};

    // ---- phase load: copy one phase's frags+bias from ws into LDS ----
    auto load_lds = [&](int ph) {
        u32x4* dstF = (u32x4*)lds;
        const u32x4* srcF = (const u32x4*)(ws + WS_FRAG) + ph * 3072;
#pragma unroll 4
        for (int i = lane; i < 3072; i += 64) dstF[i] = srcF[i];
        u32x4* dstB = (u32x4*)(lds + LDS_BIAS);
        const u32x4* srcB = (const u32x4*)(ws + WS_BIAS) + ph * 96;
        for (int i = lane; i < 96; i += 64) dstB[i] = srcB[i];
        __syncthreads();
    };

    const bfrag8* fragL = (const bfrag8*)lds;           // [(l*2+c)*8+t]*64 + lane
    const f32x4*  biasL = (const f32x4*)(lds + LDS_BIAS); // [l*32 + 8q + t]
    auto fA = [&](int l, int c, int t) { return fragL[((l * 2 + c) * 8 + t) * 64 + lane]; };

    // ---- small operators in registers ----
    bfrag8 winF[2];
    winF[0] = ((const bfrag8*)(ws + WS_WIN))[lane];
    winF[1] = ((const bfrag8*)(ws + WS_WIN))[64 + lane];
    f32x4 winBv[2];
#pragma unroll
    for (int t = 0; t < 2; ++t)
#pragma unroll
        for (int r = 0; r < 4; ++r) winBv[t][r] = Win_b[8 * q + 4 * t + r];
    bfrag8 woutF = ((const bfrag8*)(ws + WS_WOUT))[lane];
    const float wb0 = Wout_b[0], wb1 = Wout_b[1], wb2 = Wout_b[2], wb3 = Wout_b[3];

    // ---- uniform Kalman constants (scalar-loaded -> SGPRs) ----
    const float rx = Rx_[0] * Rx_[0], ry = Ry_[0] * Ry_[0];
    const float gX0 = Gx[0], gX1 = Gx[1], gX2 = Gx[2];
    const float gY0 = Gy[0], gY1 = Gy[1], gY2 = Gy[2];
    const float gx00 = gX0*gX0, gx01 = gX0*gX1, gx02 = gX0*gX2,
                gx11 = gX1*gX1, gx12 = gX1*gX2, gx22 = gX2*gX2;
    const float gy00 = gY0*gY0, gy01 = gY0*gY1, gy02 = gY0*gY2,
                gy11 = gY1*gY1, gy12 = gY1*gY2, gy22 = gY2*gY2;
    const float sx2 = max_ax[0] * max_ax[0], sy2 = max_ay[0] * max_ay[0];
    const float ex00 = gx00*sx2, ex01 = gx01*sx2, ex02 = gx02*sx2,
                ex11 = gx11*sx2, ex12 = gx12*sx2, ex22 = gx22*sx2;
    const float ey00 = gy00*sy2, ey01 = gy01*sy2, ey02 = gy02*sy2,
                ey11 = gy11*sy2, ey12 = gy12*sy2, ey22 = gy22*sy2;

    // ---- Kalman state, BOTH channels per lane (duplicated across q-groups) ----
    float Xx0 = hist[be * 40 + 0], Xx1 = 0.f, Xx2 = 0.f;
    float Xy0 = hist[be * 40 + 1], Xy1 = 0.f, Xy2 = 0.f;
    const float pv = vstd[0] * vstd[0], pa = astd[0] * astd[0];
    float Px00 = rx, Px01 = 0.f, Px02 = 0.f, Px11 = pv, Px12 = 0.f, Px22 = pa;
    float Py00 = rx, Py01 = 0.f, Py02 = 0.f, Py11 = pv, Py12 = 0.f, Py22 = pa;  // ref kinit: R_x both

    float creg[3][8];
#pragma unroll
    for (int l = 0; l < 3; ++l)
#pragma unroll
        for (int t = 0; t < 8; ++t) creg[l][t] = 0.f;
    bfrag8 hfrag[3];
#pragma unroll
    for (int l = 0; l < 3; ++l) hfrag[l] = bfrag8{};

    auto sig = [](float z) { return __builtin_amdgcn_rcpf(1.f + __expf(-z)); };
    auto th  = [](float z) { return fmaf(-2.f, __builtin_amdgcn_rcpf(__expf(2.f * z) + 1.f), 1.f); };

    auto kpred9 = [](float& X0, float& X1, float& X2,
                     float& P00, float& P01, float& P02, float& P11, float& P12, float& P22,
                     float Q00, float Q01, float Q02, float Q11, float Q12, float Q22) {
        X0 = X0 + DT * X1 + HDT * X2;
        X1 = X1 + DT * X2;
        float M00 = P00 + DT * P01 + HDT * P02;
        float M01 = P01 + DT * P11 + HDT * P12;
        float M02 = P02 + DT * P12 + HDT * P22;
        float M11 = P11 + DT * P12;
        float M12 = P12 + DT * P22;
        float M22 = P22;
        P00 = M00 + DT * M01 + HDT * M02 + Q00;
        P01 = M01 + DT * M02 + Q01;
        P02 = M02 + Q02;
        P11 = M11 + DT * M12 + Q11;
        P12 = M12 + Q12;
        P22 = M22 + Q22;
    };
    auto kupd9 = [](float& X0, float& X1, float& X2,
                    float& P00, float& P01, float& P02, float& P11, float& P12, float& P22,
                    float z, float R) {
        float y = z - X0;
        float Sinv = 1.0f / (P00 + R);
        float K0 = P00 * Sinv, K1 = P01 * Sinv, K2 = P02 * Sinv;
        X0 += y * K0; X1 += y * K1; X2 += y * K2;
        float p00 = P00, p01 = P01, p02 = P02;
        P00 = p00 - K0 * p00;
        P01 = p01 - K0 * p01;
        P02 = p02 - K0 * p02;
        P11 = P11 - K1 * p01;
        P12 = P12 - K1 * p02;
        P22 = P22 - K2 * p02;
    };

    auto packf = [&](const float* v) {
        union { bfrag8 f; unsigned int u[4]; } u;
#pragma unroll
        for (int d = 0; d < 4; ++d) u.u[d] = cvtpk(v[2 * d], v[2 * d + 1]);
        return u.f;
    };

    // XP = [Xx(3), Xy(3), Px flat(9), Py flat(9), pad]; lane supplies elems 8q..8q+7
    auto build_xp = [&]() {
        float v[8];
        if (q == 0)      { v[0]=Xx0;  v[1]=Xx1;  v[2]=Xx2;  v[3]=Xy0;  v[4]=Xy1;  v[5]=Xy2;  v[6]=Px00; v[7]=Px01; }
        else if (q == 1) { v[0]=Px02; v[1]=Px01; v[2]=Px11; v[3]=Px12; v[4]=Px02; v[5]=Px12; v[6]=Px22; v[7]=Py00; }
        else if (q == 2) { v[0]=Py01; v[1]=Py02; v[2]=Py01; v[3]=Py11; v[4]=Py12; v[5]=Py02; v[6]=Py12; v[7]=Py22; }
        else             { v[0]=0.f; v[1]=0.f; v[2]=0.f; v[3]=0.f; v[4]=0.f; v[5]=0.f; v[6]=0.f; v[7]=0.f; }
        return packf(v);
    };

    auto win_x0 = [&](bfrag8 xpf) {
        f32x4 a0 = __builtin_amdgcn_mfma_f32_16x16x32_bf16(winF[0], xpf, winBv[0], 0, 0, 0);
        f32x4 a1 = __builtin_amdgcn_mfma_f32_16x16x32_bf16(winF[1], xpf, winBv[1], 0, 0, 0);
        float v[8] = { th(a0[0]), th(a0[1]), th(a0[2]), th(a0[3]),
                       th(a1[0]), th(a1[1]), th(a1[2]), th(a1[3]) };
        return packf(v);
    };

    // 3 LSTM layers, state in registers, weights streamed from LDS
    auto layers = [&](bfrag8 xf) {
#pragma unroll
        for (int l = 0; l < 3; ++l) {
            f32x4 acc[8];
#pragma unroll
            for (int t = 0; t < 8; ++t) {
                acc[t] = __builtin_amdgcn_mfma_f32_16x16x32_bf16(fA(l, 1, t), hfrag[l], biasL[l * 32 + 8 * q + t], 0, 0, 0);
                acc[t] = __builtin_amdgcn_mfma_f32_16x16x32_bf16(fA(l, 0, t), xf, acc[t], 0, 0, 0);
            }
            float cn[8], hn[8];
#pragma unroll
            for (int t = 0; t < 8; ++t) {
                float iv = sig(acc[t][0]);
                float fv = sig(acc[t][1]);
                float gv = th(acc[t][2]);
                float ov = sig(acc[t][3]);
                float c  = fmaf(fv, creg[l][t], iv * gv);
                creg[l][t] = c;
                cn[t] = c;
                hn[t] = ov * th(c);
            }
            xf = packf(cn);
            hfrag[l] = packf(hn);
        }
        return xf;
    };

    auto do_pred = [&](int tout, bfrag8 c2f) {
        f32x4 ap = __builtin_amdgcn_mfma_f32_16x16x32_bf16(woutF, c2f, zero4, 0, 0, 0);
        float a0 = ap[0] + wb0, a1 = ap[1] + wb1, a2 = ap[2] + wb2, a3 = ap[3] + wb3;
        float s0 = __shfl(a0, m), s1 = __shfl(a1, m);
        float s2 = __shfl(a2, m), s3 = __shfl(a3, m);
        Xx2 = DT * s0; Xy2 = DT * s1;
        float qsx = s2 * s2, qsy = s3 * s3;
        kpred9(Xx0, Xx1, Xx2, Px00, Px01, Px02, Px11, Px12, Px22,
               qsx * gx00, qsx * gx01, qsx * gx02, qsx * gx11, qsx * gx12, qsx * gx22);
        kpred9(Xy0, Xy1, Xy2, Py00, Py01, Py02, Py11, Py12, Py22,
               qsy * gy00, qsy * gy01, qsy * gy02, qsy * gy11, qsy * gy12, qsy * gy22);
        if (q == 0) {
            float* o = out + (size_t)be * (LEN_PRED * 5) + tout * 5;
            o[0] = Xx0; o[1] = Xy0; o[2] = sqrtf(Px00); o[3] = sqrtf(Py00); o[4] = 0.f;
        }
    };

    load_lds(0);
    bfrag8 c2f = bfrag8{};

    // ---- encoder: 19 steps, zero barriers ----
#pragma unroll 1
    for (int t = 0; t < T_HIST - 1; ++t) {
        if (t > 0) {
            float zx = hist[be * 40 + t * 2], zy = hist[be * 40 + t * 2 + 1];
            kpred9(Xx0, Xx1, Xx2, Px00, Px01, Px02, Px11, Px12, Px22, ex00, ex01, ex02, ex11, ex12, ex22);
            kupd9 (Xx0, Xx1, Xx2, Px00, Px01, Px02, Px11, Px12, Px22, zx, rx);
            kpred9(Xy0, Xy1, Xy2, Py00, Py01, Py02, Py11, Py12, Py22, ey00, ey01, ey02, ey11, ey12, ey22);
            kupd9 (Xy0, Xy1, Xy2, Py00, Py01, Py02, Py11, Py12, Py22, zy, ry);
        }
        c2f = layers(win_x0(build_xp()));
    }
    {   // finish encoder with z_19 -> decoder-initial Kalman state
        float zx = hist[be * 40 + 38], zy = hist[be * 40 + 39];
        kpred9(Xx0, Xx1, Xx2, Px00, Px01, Px02, Px11, Px12, Px22, ex00, ex01, ex02, ex11, ex12, ex22);
        kupd9 (Xx0, Xx1, Xx2, Px00, Px01, Px02, Px11, Px12, Px22, zx, rx);
        kpred9(Xy0, Xy1, Xy2, Py00, Py01, Py02, Py11, Py12, Py22, ey00, ey01, ey02, ey11, ey12, ey22);
        kupd9 (Xy0, Xy1, Xy2, Py00, Py01, Py02, Py11, Py12, Py22, zy, ry);
    }

    __syncthreads();
    load_lds(1);

    // ---- decoder: 30 steps ----
#pragma unroll 1
    for (int t = 0; t < LEN_PRED; ++t) {
        if (t > 0) do_pred(t - 1, c2f);
        c2f = layers(win_x0(build_xp()));
    }
    do_pred(LEN_PRED - 1, c2f);
}

extern "C" void kernel_launch(void* const* d_in, const int* in_sizes, int n_in,
                              void* d_out, int out_size, void* d_ws, size_t ws_size,
                              hipStream_t stream)
{
    const float* hist  = (const float*)d_in[0];
    const float* maxax = (const float*)d_in[1];
    const float* maxay = (const float*)d_in[2];
    const float* vstd  = (const float*)d_in[3];
    const float* astd  = (const float*)d_in[4];
    const float* Rx    = (const float*)d_in[5];
    const float* Ry    = (const float*)d_in[6];
    const float* Gx    = (const float*)d_in[7];
    const float* Gy    = (const float*)d_in[8];
    const float* WinW  = (const float*)d_in[9];
    const float* Winb  = (const float*)d_in[10];
    const float* eWih  = (const float*)d_in[11];
    const float* eWhh  = (const float*)d_in[12];
    const float* ebih  = (const float*)d_in[13];
    const float* ebhh  = (const float*)d_in[14];
    const float* dWih  = (const float*)d_in[15];
    const float* dWhh  = (const float*)d_in[16];
    const float* dbih  = (const float*)d_in[17];
    const float* dbhh  = (const float*)d_in[18];
    const float* WoutW = (const float*)d_in[19];
    const float* Woutb = (const float*)d_in[20];
    char* ws = (char*)d_ws;
    float* out = (float*)d_out;

    prep_kernel<<<202, 256, 0, stream>>>(WinW, eWih, eWhh, ebih, ebhh,
                                         dWih, dWhh, dbih, dbhh, WoutW, ws);
    kalman_lstm_kernel<<<512, 64, 0, stream>>>(hist, maxax, maxay, vstd, astd,
                                               Rx, Ry, Gx, Gy, Winb, Woutb,
                                               ws, out);
}

// Round 4
// 193.355 us; speedup vs baseline: 1.2992x; 1.2992x over previous
//
#include <hip/hip_runtime.h>
#include <math.h>

#define DT   0.1f
#define HDT  0.005f
#define T_HIST 20
#define LEN_PRED 30

typedef __attribute__((ext_vector_type(8))) short bfrag8;   // 8 bf16 = 4 VGPRs
typedef __attribute__((ext_vector_type(4))) float f32x4;

// d_ws layout (bytes)
#define WS_FRAG   0u        // 96 frags * 512 bf16 * 2B = 98304
#define WS_WIN    98304u    // 2 frags * 1024B
#define WS_WOUT   100352u   // 1 frag * 1024B
#define WS_BIAS   101376u   // 2*3*32*4 floats = 3072B  ([ph][l][col][gate])

static __device__ __forceinline__ unsigned short f2bf(float x) {
    union { float f; unsigned int u; } v; v.f = x;
    unsigned int r = v.u + 0x7fffu + ((v.u >> 16) & 1u);   // RNE
    return (unsigned short)(r >> 16);
}

static __device__ __forceinline__ unsigned int cvtpk(float lo, float hi) {
    unsigned int r;
    asm("v_cvt_pk_bf16_f32 %0, %1, %2" : "=v"(r) : "v"(lo), "v"(hi));
    return r;
}

// ---------------- weight prep ----------------
// Layer frag (ph,l,c,t): A[p][k] = W[gate*32+feat][k], gate=p&3, feat=8*(p>>2)+t.
// D-layout row=q*4+r -> lane (q,m) tile t reg r = gate r of cell feat 8q+t, so
// packed c/h dwords are ALREADY next-MFMA B-fragment dwords (d-th dword = feats
// 8q+2d, 8q+2d+1).
// Win frag (t): feat = 8*(p>>2)+4t+(p&3) -> lane (q,m) holds x0 feats 8q..8q+7.
// Wout frag: REPLICATED rows (p&3) -> every lane's D regs = pred0..3 (no shfl).
// Bias: [ph][l][col=feat][gate] -> one f32x4 C-in per (l,tile).
__global__ void prep_kernel(const float* __restrict__ Win_W,
                            const float* __restrict__ eWih, const float* __restrict__ eWhh,
                            const float* __restrict__ ebih, const float* __restrict__ ebhh,
                            const float* __restrict__ dWih, const float* __restrict__ dWhh,
                            const float* __restrict__ dbih, const float* __restrict__ dbhh,
                            const float* __restrict__ Wout_W,
                            char* __restrict__ ws)
{
    int i = blockIdx.x * blockDim.x + threadIdx.x;
    if (i < 49152) {
        int fi = i >> 9, within = i & 511;
        int lane = within >> 3, jj = within & 7;
        int t = fi & 7, c = (fi >> 3) & 1;
        int pl = fi >> 4;                 // ph*3 + l
        int l = pl % 3, ph = pl / 3;
        int p = lane & 15, q2 = lane >> 4;
        int gate = p & 3;
        int feat = 8 * (p >> 2) + t;
        int row = gate * 32 + feat;
        int k = q2 * 8 + jj;
        const float* W = (c == 0) ? (ph ? dWih : eWih) : (ph ? dWhh : eWhh);
        ((unsigned short*)(ws + WS_FRAG))[i] = f2bf(W[l * 4096 + row * 32 + k]);
    } else if (i < 50176) {
        int i2 = i - 49152;
        int t = i2 >> 9, within = i2 & 511;
        int lane = within >> 3, jj = within & 7;
        int p = lane & 15, q2 = lane >> 4;
        int feat = 8 * (p >> 2) + 4 * t + (p & 3);
        int k = q2 * 8 + jj;
        float v = (k < 24) ? Win_W[feat * 24 + k] : 0.f;
        ((unsigned short*)(ws + WS_WIN))[i2] = f2bf(v);
    } else if (i < 50688) {
        int i3 = i - 50176;
        int lane = i3 >> 3, jj = i3 & 7;
        int p = lane & 15, q2 = lane >> 4;
        float v = Wout_W[(p & 3) * 32 + q2 * 8 + jj];   // replicated rows
        ((unsigned short*)(ws + WS_WOUT))[i3] = f2bf(v);
    } else if (i < 51456) {
        int b = i - 50688;                 // [ph][l][col][r]
        int ph = b / 384, rem = b % 384;
        int l = rem >> 7, w2 = rem & 127;
        int col = w2 >> 2, r = w2 & 3;
        const float* bi = ph ? dbih : ebih;
        const float* bh = ph ? dbhh : ebhh;
        ((float*)(ws + WS_BIAS))[b] = bi[l * 128 + r * 32 + col] + bh[l * 128 + r * 32 + col];
    }
}

// ---------------- main kernel: 4 waves per 16 batch elems (M-split) ----------------
// Each wave owns 2 of 8 tiles (feats 8q+2wv, 8q+2wv+1). KF/Win/Wout run
// redundantly in ALL lanes (register-local, replicated Wout rows -> no shfl).
// Encoder is layer-pipelined diagonally: 1 barrier/phase, 21 phases total.
// Decoder (irreducible feedback): 3 barriers/step.
__launch_bounds__(256, 2)
__global__ void kalman_lstm_kernel(const float* __restrict__ hist,
                                   const float* __restrict__ max_ax, const float* __restrict__ max_ay,
                                   const float* __restrict__ vstd, const float* __restrict__ astd,
                                   const float* __restrict__ Rx_, const float* __restrict__ Ry_,
                                   const float* __restrict__ Gx, const float* __restrict__ Gy,
                                   const float* __restrict__ Win_b, const float* __restrict__ Wout_b,
                                   const char* __restrict__ ws, float* __restrict__ out)
{
    __shared__ __align__(16) unsigned int xchC[3][2][4][16][4]; // [layer][parity][q][m][dw]
    __shared__ __align__(16) unsigned int xchH[3][2][4][16][4];
    __shared__ __align__(16) bfrag8 xenc[T_HIST - 1][64];       // encoder x0 frags

    const int tid  = threadIdx.x;
    const int wv   = tid >> 6;
    const int lane = tid & 63;
    const int q    = lane >> 4;
    const int m    = lane & 15;
    const int be   = blockIdx.x * 16 + m;
    const f32x4 zero4 = {0.f, 0.f, 0.f, 0.f};

    const bfrag8* fragp = (const bfrag8*)(ws + WS_FRAG);
    const f32x4*  biasp = (const f32x4*)(ws + WS_BIAS);

    // ---- per-wave weights in registers: 2 tiles x (hh,ih) x 3 layers ----
    bfrag8 fragA[3][2][2];   // [l][c: 0=ih 1=hh][j]
    f32x4  biasV[3][2];
    auto load_phase = [&](int ph) {
#pragma unroll
        for (int l = 0; l < 3; ++l) {
#pragma unroll
            for (int c = 0; c < 2; ++c)
#pragma unroll
                for (int j = 0; j < 2; ++j)
                    fragA[l][c][j] = fragp[(((ph * 3 + l) * 2 + c) * 8 + (2 * wv + j)) * 64 + lane];
#pragma unroll
            for (int j = 0; j < 2; ++j)
                biasV[l][j] = biasp[ph * 96 + l * 32 + (8 * q + 2 * wv + j)];
        }
    };

    bfrag8 winF0 = ((const bfrag8*)(ws + WS_WIN))[lane];
    bfrag8 winF1 = ((const bfrag8*)(ws + WS_WIN))[64 + lane];
    f32x4 winBv[2];
#pragma unroll
    for (int t = 0; t < 2; ++t)
#pragma unroll
        for (int r = 0; r < 4; ++r) winBv[t][r] = Win_b[8 * q + 4 * t + r];
    bfrag8 woutF = ((const bfrag8*)(ws + WS_WOUT))[lane];
    const float wb0 = Wout_b[0], wb1 = Wout_b[1], wb2 = Wout_b[2], wb3 = Wout_b[3];

    // ---- uniform Kalman constants ----
    const float rx = Rx_[0] * Rx_[0], ry = Ry_[0] * Ry_[0];
    const float gX0 = Gx[0], gX1 = Gx[1], gX2 = Gx[2];
    const float gY0 = Gy[0], gY1 = Gy[1], gY2 = Gy[2];
    const float gx00 = gX0*gX0, gx01 = gX0*gX1, gx02 = gX0*gX2,
                gx11 = gX1*gX1, gx12 = gX1*gX2, gx22 = gX2*gX2;
    const float gy00 = gY0*gY0, gy01 = gY0*gY1, gy02 = gY0*gY2,
                gy11 = gY1*gY1, gy12 = gY1*gY2, gy22 = gY2*gY2;
    const float sx2 = max_ax[0] * max_ax[0], sy2 = max_ay[0] * max_ay[0];

    // ---- Kalman state (all lanes, both channels, redundant across q and wv) ----
    float Xx0 = hist[be * 40 + 0], Xx1 = 0.f, Xx2 = 0.f;
    float Xy0 = hist[be * 40 + 1], Xy1 = 0.f, Xy2 = 0.f;
    const float pv = vstd[0] * vstd[0], pa = astd[0] * astd[0];
    float Px00 = rx, Px01 = 0.f, Px02 = 0.f, Px11 = pv, Px12 = 0.f, Px22 = pa;
    float Py00 = rx, Py01 = 0.f, Py02 = 0.f, Py11 = pv, Py12 = 0.f, Py22 = pa;  // ref kinit: R_x both

    float creg[3][2];
#pragma unroll
    for (int l = 0; l < 3; ++l) { creg[l][0] = 0.f; creg[l][1] = 0.f; }

    auto sig = [](float z) { return __builtin_amdgcn_rcpf(1.f + __expf(-z)); };
    auto th  = [](float z) { return fmaf(-2.f, __builtin_amdgcn_rcpf(__expf(2.f * z) + 1.f), 1.f); };

    auto kpred9 = [](float& X0, float& X1, float& X2,
                     float& P00, float& P01, float& P02, float& P11, float& P12, float& P22,
                     float Q00, float Q01, float Q02, float Q11, float Q12, float Q22) {
        X0 = X0 + DT * X1 + HDT * X2;
        X1 = X1 + DT * X2;
        float M00 = P00 + DT * P01 + HDT * P02;
        float M01 = P01 + DT * P11 + HDT * P12;
        float M02 = P02 + DT * P12 + HDT * P22;
        float M11 = P11 + DT * P12;
        float M12 = P12 + DT * P22;
        float M22 = P22;
        P00 = M00 + DT * M01 + HDT * M02 + Q00;
        P01 = M01 + DT * M02 + Q01;
        P02 = M02 + Q02;
        P11 = M11 + DT * M12 + Q11;
        P12 = M12 + Q12;
        P22 = M22 + Q22;
    };
    auto kupd9 = [](float& X0, float& X1, float& X2,
                    float& P00, float& P01, float& P02, float& P11, float& P12, float& P22,
                    float z, float R) {
        float y = z - X0;
        float Sinv = 1.0f / (P00 + R);
        float K0 = P00 * Sinv, K1 = P01 * Sinv, K2 = P02 * Sinv;
        X0 += y * K0; X1 += y * K1; X2 += y * K2;
        float p00 = P00, p01 = P01, p02 = P02;
        P00 = p00 - K0 * p00;
        P01 = p01 - K0 * p01;
        P02 = p02 - K0 * p02;
        P11 = P11 - K1 * p01;
        P12 = P12 - K1 * p02;
        P22 = P22 - K2 * p02;
    };
    auto kf_enc_step = [&](int s) {   // predict with encoder Q, update with z_s
        float zx = hist[be * 40 + s * 2], zy = hist[be * 40 + s * 2 + 1];
        kpred9(Xx0, Xx1, Xx2, Px00, Px01, Px02, Px11, Px12, Px22,
               gx00*sx2, gx01*sx2, gx02*sx2, gx11*sx2, gx12*sx2, gx22*sx2);
        kupd9 (Xx0, Xx1, Xx2, Px00, Px01, Px02, Px11, Px12, Px22, zx, rx);
        kpred9(Xy0, Xy1, Xy2, Py00, Py01, Py02, Py11, Py12, Py22,
               gy00*sy2, gy01*sy2, gy02*sy2, gy11*sy2, gy12*sy2, gy22*sy2);
        kupd9 (Xy0, Xy1, Xy2, Py00, Py01, Py02, Py11, Py12, Py22, zy, ry);
    };

    auto packf = [&](const float* v) {
        union { bfrag8 f; unsigned int u[4]; } u;
#pragma unroll
        for (int d = 0; d < 4; ++d) u.u[d] = cvtpk(v[2 * d], v[2 * d + 1]);
        return u.f;
    };
    // XP = [Xx(3), Xy(3), Px flat(9), Py flat(9), pad]; lane supplies elems 8q..8q+7
    auto build_xp = [&]() {
        float v[8];
        if (q == 0)      { v[0]=Xx0;  v[1]=Xx1;  v[2]=Xx2;  v[3]=Xy0;  v[4]=Xy1;  v[5]=Xy2;  v[6]=Px00; v[7]=Px01; }
        else if (q == 1) { v[0]=Px02; v[1]=Px01; v[2]=Px11; v[3]=Px12; v[4]=Px02; v[5]=Px12; v[6]=Px22; v[7]=Py00; }
        else if (q == 2) { v[0]=Py01; v[1]=Py02; v[2]=Py01; v[3]=Py11; v[4]=Py12; v[5]=Py02; v[6]=Py12; v[7]=Py22; }
        else             { v[0]=0.f; v[1]=0.f; v[2]=0.f; v[3]=0.f; v[4]=0.f; v[5]=0.f; v[6]=0.f; v[7]=0.f; }
        return packf(v);
    };
    auto win_x0 = [&](bfrag8 xpf) {
        f32x4 a0 = __builtin_amdgcn_mfma_f32_16x16x32_bf16(winF0, xpf, winBv[0], 0, 0, 0);
        f32x4 a1 = __builtin_amdgcn_mfma_f32_16x16x32_bf16(winF1, xpf, winBv[1], 0, 0, 0);
        float v[8] = { th(a0[0]), th(a0[1]), th(a0[2]), th(a0[3]),
                       th(a1[0]), th(a1[1]), th(a1[2]), th(a1[3]) };
        return packf(v);
    };

    // 2 cells of layer l (this wave's tiles): gates + packed c/h dwords
    auto lstm_cells = [&](int l, bfrag8 xf, bfrag8 hf, unsigned int& cdw, unsigned int& hdw) {
        float cj[2], hj[2];
#pragma unroll
        for (int j = 0; j < 2; ++j) {
            f32x4 a = __builtin_amdgcn_mfma_f32_16x16x32_bf16(fragA[l][1][j], hf, biasV[l][j], 0, 0, 0);
            a = __builtin_amdgcn_mfma_f32_16x16x32_bf16(fragA[l][0][j], xf, a, 0, 0, 0);
            float iv = sig(a[0]), fv = sig(a[1]), gv = th(a[2]), ov = sig(a[3]);
            float c = fmaf(fv, creg[l][j], iv * gv);
            creg[l][j] = c;
            cj[j] = c;
            hj[j] = ov * th(c);
        }
        cdw = cvtpk(cj[0], cj[1]);
        hdw = cvtpk(hj[0], hj[1]);
    };

    bfrag8 c2f = bfrag8{};
    auto do_pred = [&](int tout) {
        f32x4 ap = __builtin_amdgcn_mfma_f32_16x16x32_bf16(woutF, c2f, zero4, 0, 0, 0);
        float p0 = ap[0] + wb0, p1 = ap[1] + wb1, p2 = ap[2] + wb2, p3 = ap[3] + wb3;
        Xx2 = DT * p0; Xy2 = DT * p1;
        float qsx = p2 * p2, qsy = p3 * p3;
        kpred9(Xx0, Xx1, Xx2, Px00, Px01, Px02, Px11, Px12, Px22,
               qsx*gx00, qsx*gx01, qsx*gx02, qsx*gx11, qsx*gx12, qsx*gx22);
        kpred9(Xy0, Xy1, Xy2, Py00, Py01, Py02, Py11, Py12, Py22,
               qsy*gy00, qsy*gy01, qsy*gy02, qsy*gy11, qsy*gy12, qsy*gy22);
        if (wv == 0 && q == 0) {
            float* o = out + (size_t)be * (LEN_PRED * 5) + tout * 5;
            o[0] = Xx0; o[1] = Xy0; o[2] = sqrtf(Px00); o[3] = sqrtf(Py00); o[4] = 0.f;
        }
    };

    // ---- LDS zero init (h,c initial = 0 for both parities) ----
    for (int i = tid; i < 3 * 2 * 4 * 16 * 4; i += 256) {
        (&xchC[0][0][0][0][0])[i] = 0;
        (&xchH[0][0][0][0][0])[i] = 0;
    }

    load_phase(0);

    // ---- prologue: all lanes run encoder KF + Win redundantly; wv0 writes xenc ----
#pragma unroll 1
    for (int s = 0; s < T_HIST - 1; ++s) {
        if (s > 0) kf_enc_step(s);
        bfrag8 x0f = win_x0(build_xp());
        if (wv == 0) xenc[s][lane] = x0f;
    }
    kf_enc_step(T_HIST - 1);      // z_19 -> decoder-initial KF state (in regs, all lanes)
    __syncthreads();              // xenc + zero-init visible

    // ---- encoder: diagonal pipeline, phases p = 0..20, ONE barrier each ----
    // phase p: L0 step p, L1 step p-1, L2 step p-2. Writes parity p&1, reads p&1^1.
#pragma unroll 1
    for (int p = 0; p < T_HIST + 1; ++p) {
        const int pw = p & 1, pr = pw ^ 1;
        const bool a0 = (p <= T_HIST - 2);
        const bool a1 = (p >= 1) && (p <= T_HIST - 1);
        const bool a2 = (p >= 2);
        unsigned int cd0, hd0, cd1, hd1, cd2, hd2;
        if (a0) {
            bfrag8 xf = xenc[p][lane];
            bfrag8 hf = *(const bfrag8*)&xchH[0][pr][q][m][0];
            lstm_cells(0, xf, hf, cd0, hd0);
        }
        if (a1) {
            bfrag8 xf = *(const bfrag8*)&xchC[0][pr][q][m][0];
            bfrag8 hf = *(const bfrag8*)&xchH[1][pr][q][m][0];
            lstm_cells(1, xf, hf, cd1, hd1);
        }
        if (a2) {
            bfrag8 xf = *(const bfrag8*)&xchC[1][pr][q][m][0];
            bfrag8 hf = *(const bfrag8*)&xchH[2][pr][q][m][0];
            lstm_cells(2, xf, hf, cd2, hd2);
        }
        if (a0) { xchC[0][pw][q][m][wv] = cd0; xchH[0][pw][q][m][wv] = hd0; }
        if (a1) { xchC[1][pw][q][m][wv] = cd1; xchH[1][pw][q][m][wv] = hd1; }
        if (a2) { xchC[2][pw][q][m][wv] = cd2; xchH[2][pw][q][m][wv] = hd2; }
        __syncthreads();
    }

    // ---- decoder start: collect final h frags / c2 from pipeline parities ----
    // h0[18] written @p18(par0), h1[18] @p19(par1), h2[18]/c2[18] @p20(par0)
    load_phase(1);
    bfrag8 hfragR[3];
    hfragR[0] = *(const bfrag8*)&xchH[0][0][q][m][0];
    hfragR[1] = *(const bfrag8*)&xchH[1][1][q][m][0];
    hfragR[2] = *(const bfrag8*)&xchH[2][0][q][m][0];
    c2f       = *(const bfrag8*)&xchC[2][0][q][m][0];
    __syncthreads();   // protect reads from decoder overwrites

    // ---- decoder: 30 steps, 3 barriers/step, KF/Win/Wout all-lane local ----
#pragma unroll 1
    for (int t = 0; t < LEN_PRED; ++t) {
        if (t > 0) do_pred(t - 1);
        bfrag8 xf = win_x0(build_xp());
#pragma unroll
        for (int l = 0; l < 3; ++l) {
            unsigned int cdw, hdw;
            lstm_cells(l, xf, hfragR[l], cdw, hdw);
            xchC[l][0][q][m][wv] = cdw;
            xchH[l][0][q][m][wv] = hdw;
            __syncthreads();
            xf        = *(const bfrag8*)&xchC[l][0][q][m][0];
            hfragR[l] = *(const bfrag8*)&xchH[l][0][q][m][0];
        }
        c2f = xf;
    }
    do_pred(LEN_PRED - 1);
}

extern "C" void kernel_launch(void* const* d_in, const int* in_sizes, int n_in,
                              void* d_out, int out_size, void* d_ws, size_t ws_size,
                              hipStream_t stream)
{
    const float* hist  = (const float*)d_in[0];
    const float* maxax = (const float*)d_in[1];
    const float* maxay = (const float*)d_in[2];
    const float* vstd  = (const float*)d_in[3];
    const float* astd  = (const float*)d_in[4];
    const float* Rx    = (const float*)d_in[5];
    const float* Ry    = (const float*)d_in[6];
    const float* Gx    = (const float*)d_in[7];
    const float* Gy    = (const float*)d_in[8];
    const float* WinW  = (const float*)d_in[9];
    const float* Winb  = (const float*)d_in[10];
    const float* eWih  = (const float*)d_in[11];
    const float* eWhh  = (const float*)d_in[12];
    const float* ebih  = (const float*)d_in[13];
    const float* ebhh  = (const float*)d_in[14];
    const float* dWih  = (const float*)d_in[15];
    const float* dWhh  = (const float*)d_in[16];
    const float* dbih  = (const float*)d_in[17];
    const float* dbhh  = (const float*)d_in[18];
    const float* WoutW = (const float*)d_in[19];
    const float* Woutb = (const float*)d_in[20];
    char* ws = (char*)d_ws;
    float* out = (float*)d_out;

    prep_kernel<<<202, 256, 0, stream>>>(WinW, eWih, eWhh, ebih, ebhh,
                                         dWih, dWhh, dbih, dbhh, WoutW, ws);
    kalman_lstm_kernel<<<512, 256, 0, stream>>>(hist, maxax, maxay, vstd, astd,
                                                Rx, Ry, Gx, Gy, Winb, Woutb,
                                                ws, out);
}